// Round 1
// baseline (218.192 us; speedup 1.0000x reference)
//
#include <hip/hip_runtime.h>
#include <hip/hip_bf16.h>

#define NC 24

__device__ __forceinline__ float softplus_abs(float x) {
    // log1p(exp(-|x|))
    return log1pf(expf(-fabsf(x)));
}

// Per-target losses + scatter of the objectness mask bit.
// acc[0]=lb_sum, acc[1]=lo_pos_sum, acc[2]=lc_sum (shared across scales)
__global__ void det_target_kernel(const float* __restrict__ cls_pred,
                                  const float* __restrict__ reg_pred,
                                  const float* __restrict__ tgt,
                                  int B, int T, int H, int W,
                                  unsigned int* __restrict__ mask,
                                  float* __restrict__ acc) {
    int i = blockIdx.x * blockDim.x + threadIdx.x;
    float lb = 0.f, lo = 0.f, lc = 0.f;
    if (i < B * T) {
        int b = i / T;
        const float* tp = tgt + (size_t)i * 6;
        int   tcls = (int)tp[0];
        float tx = tp[1] * (float)W;
        float ty = tp[2] * (float)H;
        float tw = tp[3] * (float)W;
        float th = tp[4] * (float)H;
        int gx = min(max((int)tx, 0), W - 1);
        int gy = min(max((int)ty, 0), H - 1);
        size_t hw   = (size_t)H * W;
        size_t cell = (size_t)gy * W + gx;

        // ---- bbox smooth-L1 ----
        size_t regbase = (size_t)b * 4 * hw + cell;
        float r0 = reg_pred[regbase];
        float r1 = reg_pred[regbase + hw];
        float r2 = reg_pred[regbase + 2 * hw];
        float r3 = reg_pred[regbase + 3 * hw];
        float px = fminf(fmaxf((float)gx + r0, 0.f), (float)W);
        float py = fminf(fmaxf((float)gy + r1, 0.f), (float)H);
        float pw = fminf(fmaxf(expf(r2), 1.f), (float)W) * 0.1f;
        float ph = fminf(fmaxf(expf(r3), 1.f), (float)H) * 0.1f;
        float pb0 = px - pw * 0.5f, pb1 = py - ph * 0.5f;
        float pb2 = px + pw * 0.5f, pb3 = py + ph * 0.5f;
        float tb0 = tx - tw * 0.5f, tb1 = ty - th * 0.5f;
        float tb2 = tx + tw * 0.5f, tb3 = ty + th * 0.5f;
        float s = 0.f;
        {
            float d, ad;
            d = pb0 - tb0; ad = fabsf(d); s += (ad < 1.f) ? 0.5f * d * d : ad - 0.5f;
            d = pb1 - tb1; ad = fabsf(d); s += (ad < 1.f) ? 0.5f * d * d : ad - 0.5f;
            d = pb2 - tb2; ad = fabsf(d); s += (ad < 1.f) ? 0.5f * d * d : ad - 0.5f;
            d = pb3 - tb3; ad = fabsf(d); s += (ad < 1.f) ? 0.5f * d * d : ad - 0.5f;
        }
        lb = s * 0.25f;

        // ---- positive objectness BCE (z=1) ----
        size_t clsbase = (size_t)b * (NC + 1) * hw + cell;
        float obj = cls_pred[clsbase];
        lo = fmaxf(obj, 0.f) - obj + softplus_abs(obj);

        // ---- focal classification loss ----
        float fs = 0.f;
        #pragma unroll
        for (int c = 0; c < NC; c++) {
            float x = cls_pred[clsbase + (size_t)(c + 1) * hw];
            float z = (tcls == c && tcls < NC) ? 1.f : 0.f;
            float bce = fmaxf(x, 0.f) - x * z + softplus_abs(x);
            float p  = 1.f / (1.f + expf(-x));
            float pt = p * z + (1.f - p) * (1.f - z);
            float om = 1.f - pt;
            fs += 0.25f * om * om * bce;
        }
        lc = fs * (1.f / (float)NC);

        // ---- scatter obj_tgt bit (dedup via OR) ----
        unsigned int mcell = (unsigned int)((size_t)b * hw + cell);
        atomicOr(&mask[mcell >> 5], 1u << (mcell & 31));
    }
    // wave (64-lane) reduction
    #pragma unroll
    for (int o = 32; o > 0; o >>= 1) {
        lb += __shfl_down(lb, o);
        lo += __shfl_down(lo, o);
        lc += __shfl_down(lc, o);
    }
    if ((threadIdx.x & 63) == 0) {
        atomicAdd(&acc[0], lb);
        atomicAdd(&acc[1], lo);
        atomicAdd(&acc[2], lc);
    }
}

// Negative objectness BCE over the full grid, masked by obj_tgt.
// acc2[0] = sum(bce(x,0) * neg), acc2[1] = sum(neg)
__global__ void det_grid_kernel(const float* __restrict__ cls_pred,
                                const unsigned int* __restrict__ mask,
                                int B, int H, int W, int C,
                                float* __restrict__ acc2) {
    size_t hw = (size_t)H * W;
    size_t n = (size_t)B * hw;
    float nl = 0.f, ncnt = 0.f;
    for (size_t i = (size_t)blockIdx.x * blockDim.x + threadIdx.x; i < n;
         i += (size_t)gridDim.x * blockDim.x) {
        size_t b = i / hw;
        size_t rem = i - b * hw;
        float x = cls_pred[b * (size_t)C * hw + rem];
        float neg = ((mask[i >> 5] >> (unsigned)(i & 31)) & 1u) ? 0.f : 1.f;
        nl += neg * (fmaxf(x, 0.f) + softplus_abs(x));
        ncnt += neg;
    }
    #pragma unroll
    for (int o = 32; o > 0; o >>= 1) {
        nl += __shfl_down(nl, o);
        ncnt += __shfl_down(ncnt, o);
    }
    if ((threadIdx.x & 63) == 0) {
        atomicAdd(&acc2[0], nl);
        atomicAdd(&acc2[1], ncnt);
    }
}

// acc: [0]=lb, [1]=lo_pos, [2]=lc, [3]=negloss_p4, [4]=negcnt_p4,
//      [5]=negloss_p5, [6]=negcnt_p5
__global__ void det_final_kernel(const float* __restrict__ acc,
                                 float* __restrict__ out,
                                 float n_targets, float total_grid) {
    if (threadIdx.x == 0 && blockIdx.x == 0) {
        float lb = acc[0] / n_targets;
        float lc = acc[2] / n_targets;
        float lo_sum = acc[1]
                     + acc[3] / acc[4] * 0.5f
                     + acc[5] / acc[6] * 0.5f;
        float lo = lo_sum / (total_grid + 1e-8f);
        out[0] = lb + lo + lc;
        out[1] = lb;
        out[2] = lo;
        out[3] = lc;
    }
}

extern "C" void kernel_launch(void* const* d_in, const int* in_sizes, int n_in,
                              void* d_out, int out_size, void* d_ws, size_t ws_size,
                              hipStream_t stream) {
    const float* cls4 = (const float*)d_in[0];
    const float* reg4 = (const float*)d_in[1];
    const float* cls5 = (const float*)d_in[2];
    const float* reg5 = (const float*)d_in[3];
    const float* tgt4 = (const float*)d_in[4];
    const float* tgt5 = (const float*)d_in[5];
    float* out = (float*)d_out;

    const int B = 32, H4 = 128, W4 = 128, H5 = 64, W5 = 64, T4 = 200, T5 = 100;
    const int C = NC + 1;

    // workspace layout: 256B accumulators | mask_p4 bits | mask_p5 bits
    float* acc = (float*)d_ws;
    unsigned int* mask4 = (unsigned int*)((char*)d_ws + 256);
    const size_t mask4_bytes = ((size_t)B * H4 * W4) / 8;   // 65536
    unsigned int* mask5 = (unsigned int*)((char*)d_ws + 256 + mask4_bytes);
    const size_t mask5_bytes = ((size_t)B * H5 * W5) / 8;   // 16384

    hipMemsetAsync(d_ws, 0, 256 + mask4_bytes + mask5_bytes, stream);

    det_target_kernel<<<(B * T4 + 255) / 256, 256, 0, stream>>>(
        cls4, reg4, tgt4, B, T4, H4, W4, mask4, acc);
    det_target_kernel<<<(B * T5 + 255) / 256, 256, 0, stream>>>(
        cls5, reg5, tgt5, B, T5, H5, W5, mask5, acc);

    det_grid_kernel<<<512, 256, 0, stream>>>(cls4, mask4, B, H4, W4, C, acc + 3);
    det_grid_kernel<<<256, 256, 0, stream>>>(cls5, mask5, B, H5, W5, C, acc + 5);

    det_final_kernel<<<1, 64, 0, stream>>>(
        acc, out,
        (float)(B * T4 + B * T5),
        (float)(B * H4 * W4 + B * H5 * W5));
}

// Round 2
// 130.290 us; speedup vs baseline: 1.6747x; 1.6747x over previous
//
#include <hip/hip_runtime.h>
#include <hip/hip_bf16.h>

#define NC 24
constexpr int B  = 32;
constexpr int H4 = 128, W4 = 128, HW4 = H4 * W4;   // 16384 = 2^14
constexpr int H5 = 64,  W5 = 64,  HW5 = H5 * W5;   // 4096  = 2^12
constexpr int T4 = 200, T5 = 100;
constexpr int N4 = B * T4;   // 6400
constexpr int N5 = B * T5;   // 3200
constexpr int C  = NC + 1;   // 25

// stage-2 grid split
constexpr int P4BLK = 160, P5BLK = 40;             // 200 blocks total
constexpr int NV4 = B * HW4 / 4;                   // 131072 float4s
constexpr int NV5 = B * HW5 / 4;                   // 32768 float4s

// ws layout (bytes)
constexpr size_t PART1_OFF = 0;        // 38 blocks * 4 floats = 608 B
constexpr size_t PART2_OFF = 1024;     // 200 blocks * 2 floats = 1600 B
constexpr size_t MASK4_OFF = 4096;     // 65536 B
constexpr size_t MASK5_OFF = MASK4_OFF + 65536;    // 16384 B
constexpr size_t MASK_BYTES = 65536 + 16384;

__device__ __forceinline__ float softplus_abs(float x) { return log1pf(expf(-fabsf(x))); }
__device__ __forceinline__ float bce_neg(float x) { return fmaxf(x, 0.f) + softplus_abs(x); }

__device__ __forceinline__ void target_losses(
    const float* __restrict__ cls, const float* __restrict__ reg,
    const float* __restrict__ tgt, unsigned int* __restrict__ mask,
    int i, int T, int W, int H, int HW,
    float& lb, float& lo, float& lc) {
    int b = i / T;
    const float* tp = tgt + (size_t)i * 6;
    int   tcls = (int)tp[0];
    float tx = tp[1] * (float)W;
    float ty = tp[2] * (float)H;
    float tw = tp[3] * (float)W;
    float th = tp[4] * (float)H;
    int gx = min(max((int)tx, 0), W - 1);
    int gy = min(max((int)ty, 0), H - 1);
    int cell = gy * W + gx;

    // bbox smooth-L1
    size_t regbase = (size_t)b * 4 * HW + cell;
    float r0 = reg[regbase];
    float r1 = reg[regbase + HW];
    float r2 = reg[regbase + 2 * (size_t)HW];
    float r3 = reg[regbase + 3 * (size_t)HW];
    float px = fminf(fmaxf((float)gx + r0, 0.f), (float)W);
    float py = fminf(fmaxf((float)gy + r1, 0.f), (float)H);
    float pw = fminf(fmaxf(expf(r2), 1.f), (float)W) * 0.1f;
    float ph = fminf(fmaxf(expf(r3), 1.f), (float)H) * 0.1f;
    float pb[4] = { px - pw * 0.5f, py - ph * 0.5f, px + pw * 0.5f, py + ph * 0.5f };
    float tb[4] = { tx - tw * 0.5f, ty - th * 0.5f, tx + tw * 0.5f, ty + th * 0.5f };
    float s = 0.f;
    #pragma unroll
    for (int k = 0; k < 4; k++) {
        float d = pb[k] - tb[k];
        float ad = fabsf(d);
        s += (ad < 1.f) ? 0.5f * d * d : ad - 0.5f;
    }
    lb = s * 0.25f;

    // positive objectness BCE (z=1)
    size_t clsbase = (size_t)b * C * HW + cell;
    float obj = cls[clsbase];
    lo = fmaxf(obj, 0.f) - obj + softplus_abs(obj);

    // focal classification loss (mean over NC)
    float fs = 0.f;
    #pragma unroll
    for (int c = 0; c < NC; c++) {
        float x = cls[clsbase + (size_t)(c + 1) * HW];
        float z = (tcls == c && tcls < NC) ? 1.f : 0.f;
        float bce = fmaxf(x, 0.f) - x * z + softplus_abs(x);
        float p  = 1.f / (1.f + expf(-x));
        float pt = p * z + (1.f - p) * (1.f - z);
        float om = 1.f - pt;
        fs += 0.25f * om * om * bce;
    }
    lc = fs * (1.f / (float)NC);

    // scatter obj_tgt bit (dedup via OR; scattered addresses -> pipelined)
    unsigned int mcell = (unsigned int)(b * HW + cell);
    atomicOr(&mask[mcell >> 5], 1u << (mcell & 31));
}

// Stage 1: both scales' per-target losses; per-block partials (no global atomics).
__global__ __launch_bounds__(256) void det_stage1(
    const float* __restrict__ cls4, const float* __restrict__ reg4,
    const float* __restrict__ tgt4, const float* __restrict__ cls5,
    const float* __restrict__ reg5, const float* __restrict__ tgt5,
    unsigned int* __restrict__ mask4, unsigned int* __restrict__ mask5,
    float* __restrict__ part1) {
    int tid = blockIdx.x * 256 + threadIdx.x;
    float lb = 0.f, lo = 0.f, lc = 0.f;
    if (tid < N4) {
        target_losses(cls4, reg4, tgt4, mask4, tid, T4, W4, H4, HW4, lb, lo, lc);
    } else if (tid < N4 + N5) {
        target_losses(cls5, reg5, tgt5, mask5, tid - N4, T5, W5, H5, HW5, lb, lo, lc);
    }
    #pragma unroll
    for (int o = 32; o > 0; o >>= 1) {
        lb += __shfl_down(lb, o);
        lo += __shfl_down(lo, o);
        lc += __shfl_down(lc, o);
    }
    __shared__ float red[4][3];
    int wv = threadIdx.x >> 6, ln = threadIdx.x & 63;
    if (ln == 0) { red[wv][0] = lb; red[wv][1] = lo; red[wv][2] = lc; }
    __syncthreads();
    if (threadIdx.x == 0) {
        part1[blockIdx.x * 4 + 0] = red[0][0] + red[1][0] + red[2][0] + red[3][0];
        part1[blockIdx.x * 4 + 1] = red[0][1] + red[1][1] + red[2][1] + red[3][1];
        part1[blockIdx.x * 4 + 2] = red[0][2] + red[1][2] + red[2][2] + red[3][2];
    }
}

// Stage 2: masked negative-obj BCE over both grids, float4, per-block partials.
__global__ __launch_bounds__(256) void det_stage2(
    const float* __restrict__ cls4, const float* __restrict__ cls5,
    const unsigned int* __restrict__ mask4, const unsigned int* __restrict__ mask5,
    float* __restrict__ part2) {
    float nl = 0.f, ncnt = 0.f;
    if (blockIdx.x < P4BLK) {
        for (int v = blockIdx.x * 256 + threadIdx.x; v < NV4; v += P4BLK * 256) {
            int i = v * 4;                       // cell index within scale
            int b = i >> 14;                     // / HW4
            int rem = i & (HW4 - 1);
            const float4 x = *(const float4*)(cls4 + (size_t)b * C * HW4 + rem);
            unsigned int bits = (mask4[i >> 5] >> (unsigned)(i & 31)) & 0xFu;
            nl += (bits & 1u) ? 0.f : bce_neg(x.x);
            nl += (bits & 2u) ? 0.f : bce_neg(x.y);
            nl += (bits & 4u) ? 0.f : bce_neg(x.z);
            nl += (bits & 8u) ? 0.f : bce_neg(x.w);
            ncnt += (float)(4 - __popc(bits));
        }
    } else {
        int blk = blockIdx.x - P4BLK;
        for (int v = blk * 256 + threadIdx.x; v < NV5; v += P5BLK * 256) {
            int i = v * 4;
            int b = i >> 12;                     // / HW5
            int rem = i & (HW5 - 1);
            const float4 x = *(const float4*)(cls5 + (size_t)b * C * HW5 + rem);
            unsigned int bits = (mask5[i >> 5] >> (unsigned)(i & 31)) & 0xFu;
            nl += (bits & 1u) ? 0.f : bce_neg(x.x);
            nl += (bits & 2u) ? 0.f : bce_neg(x.y);
            nl += (bits & 4u) ? 0.f : bce_neg(x.z);
            nl += (bits & 8u) ? 0.f : bce_neg(x.w);
            ncnt += (float)(4 - __popc(bits));
        }
    }
    #pragma unroll
    for (int o = 32; o > 0; o >>= 1) {
        nl += __shfl_down(nl, o);
        ncnt += __shfl_down(ncnt, o);
    }
    __shared__ float red[4][2];
    int wv = threadIdx.x >> 6, ln = threadIdx.x & 63;
    if (ln == 0) { red[wv][0] = nl; red[wv][1] = ncnt; }
    __syncthreads();
    if (threadIdx.x == 0) {
        part2[blockIdx.x * 2 + 0] = red[0][0] + red[1][0] + red[2][0] + red[3][0];
        part2[blockIdx.x * 2 + 1] = red[0][1] + red[1][1] + red[2][1] + red[3][1];
    }
}

// Stage 3: one wave sums all partials and writes the 4 outputs.
__global__ __launch_bounds__(64) void det_final(
    const float* __restrict__ part1, const float* __restrict__ part2,
    float* __restrict__ out) {
    int t = threadIdx.x;
    float lb = 0.f, lo = 0.f, lc = 0.f, nl4 = 0.f, nc4 = 0.f, nl5 = 0.f, nc5 = 0.f;
    for (int k = t; k < 38; k += 64) {
        lb += part1[k * 4 + 0];
        lo += part1[k * 4 + 1];
        lc += part1[k * 4 + 2];
    }
    for (int k = t; k < P4BLK; k += 64) {
        nl4 += part2[k * 2 + 0];
        nc4 += part2[k * 2 + 1];
    }
    for (int k = t; k < P5BLK; k += 64) {
        nl5 += part2[(P4BLK + k) * 2 + 0];
        nc5 += part2[(P4BLK + k) * 2 + 1];
    }
    #pragma unroll
    for (int o = 32; o > 0; o >>= 1) {
        lb  += __shfl_down(lb, o);
        lo  += __shfl_down(lo, o);
        lc  += __shfl_down(lc, o);
        nl4 += __shfl_down(nl4, o);
        nc4 += __shfl_down(nc4, o);
        nl5 += __shfl_down(nl5, o);
        nc5 += __shfl_down(nc5, o);
    }
    if (t == 0) {
        float n = (float)(N4 + N5);
        float lbn = lb / n;
        float lcn = lc / n;
        float lo_sum = lo + nl4 / nc4 * 0.5f + nl5 / nc5 * 0.5f;
        float lon = lo_sum / ((float)(B * HW4 + B * HW5) + 1e-8f);
        out[0] = lbn + lon + lcn;
        out[1] = lbn;
        out[2] = lon;
        out[3] = lcn;
    }
}

extern "C" void kernel_launch(void* const* d_in, const int* in_sizes, int n_in,
                              void* d_out, int out_size, void* d_ws, size_t ws_size,
                              hipStream_t stream) {
    const float* cls4 = (const float*)d_in[0];
    const float* reg4 = (const float*)d_in[1];
    const float* cls5 = (const float*)d_in[2];
    const float* reg5 = (const float*)d_in[3];
    const float* tgt4 = (const float*)d_in[4];
    const float* tgt5 = (const float*)d_in[5];
    float* out = (float*)d_out;

    float* part1 = (float*)((char*)d_ws + PART1_OFF);
    float* part2 = (float*)((char*)d_ws + PART2_OFF);
    unsigned int* mask4 = (unsigned int*)((char*)d_ws + MASK4_OFF);
    unsigned int* mask5 = (unsigned int*)((char*)d_ws + MASK5_OFF);

    hipMemsetAsync((char*)d_ws + MASK4_OFF, 0, MASK_BYTES, stream);

    det_stage1<<<(N4 + N5 + 255) / 256, 256, 0, stream>>>(
        cls4, reg4, tgt4, cls5, reg5, tgt5, mask4, mask5, part1);

    det_stage2<<<P4BLK + P5BLK, 256, 0, stream>>>(cls4, cls5, mask4, mask5, part2);

    det_final<<<1, 64, 0, stream>>>(part1, part2, out);
}